// Round 3
// baseline (5131.435 us; speedup 1.0000x reference)
//
#include <hip/hip_runtime.h>
#include <hip/hip_bf16.h>

#define NTOK 9216   // H*W
#define CCH  256    // C
#define DQK  32     // CQ
#define BJ   16     // j-columns per attention block
#define CI   64     // i-chunk per iteration
#define QS   36     // qsh row stride (floats), 144B rows (16B aligned)
#define PS   20     // psh row stride (floats), 80B rows (16B aligned)

typedef __attribute__((ext_vector_type(4))) float f32x4;

// ---------------- Kernel 1: QKV projection (all fp32) ----------------
// qkv[o][n] = sum_c w[o][c] * x[b][c][n]
//   o in [0,32)   -> qT[b][n][o]        (fp32, n x 32)
//   o in [32,64)  -> kT[b][n][o-32]     (fp32, n x 32)
//   o in [64,320) -> vnc[b][n][o-64]    (fp32, n x 256)  [i][c] for coalesced PV
__global__ __launch_bounds__(256) void qkv_kernel(
    const float* __restrict__ x, const float* __restrict__ w,
    float* __restrict__ qT, float* __restrict__ kT, float* __restrict__ vnc)
{
    const int t  = threadIdx.x;
    const int n  = blockIdx.x * 256 + t;
    const int o0 = blockIdx.y * 32;
    const int b  = blockIdx.z;
    const float* xb = x + (size_t)b * CCH * NTOK + n;
    const float* wr = w + (size_t)o0 * CCH;   // uniform address -> s_load

    float acc[32];
#pragma unroll
    for (int o = 0; o < 32; ++o) acc[o] = 0.f;

#pragma unroll 4
    for (int c = 0; c < CCH; ++c) {
        float xv = xb[(size_t)c * NTOK];
#pragma unroll
        for (int o = 0; o < 32; ++o)
            acc[o] += wr[o * CCH + c] * xv;
    }

    float* dst;
    if (o0 == 0)       dst = qT + ((size_t)b * NTOK + n) * DQK;
    else if (o0 == 32) dst = kT + ((size_t)b * NTOK + n) * DQK;
    else               dst = vnc + ((size_t)b * NTOK + n) * CCH + (o0 - 64);
#pragma unroll
    for (int o = 0; o < 32; ++o) dst[o] = acc[o];
}

// ---------------- Kernel 2: attention, pure fp32 VALU ----------------
// S[i][j] = sum_d qT[i][d]*kT[j][d];  P = exp(S) (scores bounded ~23, fits fp32);
// l[j] = sum_i P[i][j];  O[c][j] = sum_i P[i][j]*v[i][c];
// out[b][c][j] = gamma*O[c][j]/l[j] + x[b][c][j]
__global__ __launch_bounds__(256) void attn_kernel(
    const float* __restrict__ qT, const float* __restrict__ kT,
    const float* __restrict__ vnc, const float* __restrict__ x,
    const float* __restrict__ gamma, float* __restrict__ out)
{
    __shared__ __align__(16) float qsh[CI * QS];   // 9216 B
    __shared__ __align__(16) float psh[CI * PS];   // 5120 B
    __shared__ float lred[32 * 16];                // 2048 B
    __shared__ float lfin[16];

    const int t  = threadIdx.x;
    const int b  = blockIdx.y;
    const int j0 = blockIdx.x * BJ;
    const int jl = t & 7;    // QK phase: j-columns {jl, jl+8}
    const int ig = t >> 3;   // QK phase: i-rows {2ig, 2ig+1}

    // k rows for this thread's two j columns, cached in registers
    f32x4 kreg[2][8];
#pragma unroll
    for (int s = 0; s < 2; ++s) {
        const float* kr = kT + ((size_t)b * NTOK + j0 + jl + 8 * s) * DQK;
#pragma unroll
        for (int u = 0; u < 8; ++u) kreg[s][u] = *(const f32x4*)(kr + 4 * u);
    }

    float Oacc[16];
#pragma unroll
    for (int j = 0; j < 16; ++j) Oacc[j] = 0.f;
    float lw0 = 0.f, lw1 = 0.f;

    const float* vbase = vnc + (size_t)b * NTOK * CCH + t;  // c = t

    for (int i0 = 0; i0 < NTOK; i0 += CI) {
        // stage q chunk: 64 rows x 32 floats (contiguous source), padded rows in LDS
        {
            const float* src = qT + ((size_t)b * NTOK + i0) * DQK;
#pragma unroll
            for (int h = 0; h < 2; ++h) {
                int f = t + 256 * h;          // flat float4 index in [0,512)
                int row = f >> 3, q4 = (f & 7) * 4;
                *(f32x4*)&qsh[row * QS + q4] = *(const f32x4*)(src + row * 32 + q4);
            }
        }
        __syncthreads();

        // QK + exp: thread computes p for (il = 2ig+r, j = jl and jl+8)
#pragma unroll
        for (int r = 0; r < 2; ++r) {
            int il = 2 * ig + r;
            float s0 = 0.f, s1 = 0.f;
#pragma unroll
            for (int u = 0; u < 8; ++u) {
                f32x4 qv = *(const f32x4*)&qsh[il * QS + 4 * u];
                s0 += qv[0] * kreg[0][u][0] + qv[1] * kreg[0][u][1]
                    + qv[2] * kreg[0][u][2] + qv[3] * kreg[0][u][3];
                s1 += qv[0] * kreg[1][u][0] + qv[1] * kreg[1][u][1]
                    + qv[2] * kreg[1][u][2] + qv[3] * kreg[1][u][3];
            }
            float p0 = __expf(s0), p1 = __expf(s1);
            lw0 += p0; lw1 += p1;
            psh[il * PS + jl]     = p0;
            psh[il * PS + jl + 8] = p1;
        }
        __syncthreads();

        // PV: thread t = channel c; broadcast psh rows, coalesced v lines
        const float* vr = vbase + (size_t)i0 * CCH;
#pragma unroll 4
        for (int il = 0; il < CI; ++il) {
            float vv = vr[(size_t)il * CCH];
            f32x4 pA = *(const f32x4*)&psh[il * PS];
            f32x4 pB = *(const f32x4*)&psh[il * PS + 4];
            f32x4 pC = *(const f32x4*)&psh[il * PS + 8];
            f32x4 pD = *(const f32x4*)&psh[il * PS + 12];
            Oacc[0]  += pA[0] * vv; Oacc[1]  += pA[1] * vv;
            Oacc[2]  += pA[2] * vv; Oacc[3]  += pA[3] * vv;
            Oacc[4]  += pB[0] * vv; Oacc[5]  += pB[1] * vv;
            Oacc[6]  += pB[2] * vv; Oacc[7]  += pB[3] * vv;
            Oacc[8]  += pC[0] * vv; Oacc[9]  += pC[1] * vv;
            Oacc[10] += pC[2] * vv; Oacc[11] += pC[3] * vv;
            Oacc[12] += pD[0] * vv; Oacc[13] += pD[1] * vv;
            Oacc[14] += pD[2] * vv; Oacc[15] += pD[3] * vv;
        }
        __syncthreads(); // protect qsh/psh before next chunk overwrites
    }

    // l[j] reduction: per-thread partials -> 32 groups x 16 cols -> 16 totals
    lred[ig * 16 + jl]     = lw0;
    lred[ig * 16 + jl + 8] = lw1;
    __syncthreads();
    if (t < 16) {
        float l = 0.f;
#pragma unroll
        for (int g = 0; g < 32; ++g) l += lred[g * 16 + t];
        lfin[t] = l;
    }
    __syncthreads();

    // epilogue: out[b][c=t][j0+j] = gamma*Oacc[j]/l[j] + x
    const float gm = gamma[0];
    size_t gaddr = ((size_t)b * CCH + t) * NTOK + j0;
#pragma unroll
    for (int u = 0; u < 4; ++u) {
        f32x4 xv = *(const f32x4*)(x + gaddr + 4 * u);
        f32x4 o4;
#pragma unroll
        for (int e = 0; e < 4; ++e)
            o4[e] = gm * Oacc[4 * u + e] / lfin[4 * u + e] + xv[e];
        *(f32x4*)(out + gaddr + 4 * u) = o4;
    }
}

extern "C" void kernel_launch(void* const* d_in, const int* in_sizes, int n_in,
                              void* d_out, int out_size, void* d_ws, size_t ws_size,
                              hipStream_t stream) {
    const float* x     = (const float*)d_in[0];
    const float* w     = (const float*)d_in[1];
    const float* gamma = (const float*)d_in[2];
    float* out = (float*)d_out;

    float* qT  = (float*)d_ws;                      // 2*9216*32  fp32 = 2.36 MB
    float* kT  = qT + (size_t)2 * NTOK * DQK;       // 2*9216*32  fp32 = 2.36 MB
    float* vnc = kT + (size_t)2 * NTOK * DQK;       // 2*9216*256 fp32 = 18.9 MB

    dim3 g1(NTOK / 256, 320 / 32, 2);
    qkv_kernel<<<g1, 256, 0, stream>>>(x, w, qT, kT, vnc);

    dim3 g2(NTOK / BJ, 2);
    attn_kernel<<<g2, 256, 0, stream>>>(qT, kT, vnc, x, gamma, out);
}

// Round 4
// 821.027 us; speedup vs baseline: 6.2500x; 6.2500x over previous
//
#include <hip/hip_runtime.h>
#include <hip/hip_bf16.h>

#define NTOK 9216   // H*W
#define CCH  256    // C
#define DQK  32     // CQ
#define BJ   64     // j-columns per attention block
#define BI   64     // i-rows per iteration
#define SI   72     // Pl row stride (shorts): 144B rows, 16B aligned
#define QS   36     // qsh row stride (floats): 144B rows, 16B aligned
#define SO   68     // epilogue LDS row stride (floats)

typedef __attribute__((ext_vector_type(8))) short short8;
typedef __attribute__((ext_vector_type(4))) float f32x4;

__device__ __forceinline__ unsigned short f2bf(float x) {
    union { float f; unsigned int u; } v; v.f = x;
    return (unsigned short)((v.u + 0x7FFF + ((v.u >> 16) & 1)) >> 16); // RNE
}

// ---------------- Kernel 1: QKV projection ----------------
// qkv[o][n] = sum_c w[o][c] * x[b][c][n]
//   o in [0,32)   -> qT[b][n][o]      (fp32, n x 32)
//   o in [32,64)  -> kT[b][n][o-32]   (fp32, n x 32)
//   o in [64,320) -> vcn[b][o-64][n]  (bf16, c x n)  for PV MFMA B-fragments
__global__ __launch_bounds__(256) void qkv_kernel(
    const float* __restrict__ x, const float* __restrict__ w,
    float* __restrict__ qT, float* __restrict__ kT,
    unsigned short* __restrict__ vcn)
{
    const int t  = threadIdx.x;
    const int n  = blockIdx.x * 256 + t;
    const int o0 = blockIdx.y * 32;
    const int b  = blockIdx.z;
    const float* xb = x + (size_t)b * CCH * NTOK + n;
    const float* wr = w + (size_t)o0 * CCH;   // uniform address -> s_load

    float acc[32];
#pragma unroll
    for (int o = 0; o < 32; ++o) acc[o] = 0.f;

#pragma unroll 4
    for (int c = 0; c < CCH; ++c) {
        float xv = xb[(size_t)c * NTOK];
#pragma unroll
        for (int o = 0; o < 32; ++o)
            acc[o] += wr[o * CCH + c] * xv;
    }

    if (o0 == 0) {
        float* dst = qT + ((size_t)b * NTOK + n) * DQK;
#pragma unroll
        for (int o = 0; o < 32; ++o) dst[o] = acc[o];
    } else if (o0 == 32) {
        float* dst = kT + ((size_t)b * NTOK + n) * DQK;
#pragma unroll
        for (int o = 0; o < 32; ++o) dst[o] = acc[o];
    } else {
        unsigned short* dst = vcn + ((size_t)b * CCH + (o0 - 64)) * NTOK + n;
#pragma unroll
        for (int o = 0; o < 32; ++o)
            dst[(size_t)o * NTOK] = f2bf(acc[o]);  // lanes coalesce along n
    }
}

// ---------------- Kernel 2: VALU QK + softmax, MFMA PV ----------------
// S[i][j] = qT[i]·kT[j] (fp32 VALU, j = lane, exact l[j]);  P=exp(S) -> LDS bf16
// O[j][c] += P^T @ V via mfma_f32_16x16x32_bf16;  out = gamma*O/l + x
__global__ __launch_bounds__(256) void attn_kernel(
    const float* __restrict__ qT, const float* __restrict__ kT,
    const unsigned short* __restrict__ vcn, const float* __restrict__ x,
    const float* __restrict__ gamma, float* __restrict__ out)
{
    // qsh [0,9216) f32 64xQS | Pl [9216,18432) bf16 64xSI | lred [18432,19456)
    // epilogue otl aliases [0,17408)
    __shared__ __align__(16) char smem[19456];
    float* qsh = (float*)smem;
    unsigned short* Pl = (unsigned short*)(smem + 9216);
    float* lred = (float*)(smem + 18432);

    const int t    = threadIdx.x;
    const int wv   = t >> 6;
    const int lane = t & 63;
    const int l15  = lane & 15;
    const int qd   = lane >> 4;
    const int j0   = blockIdx.x * BJ;
    const int b    = blockIdx.y;

    // k row for this thread's j-column (j = j0 + lane), in registers
    f32x4 kreg[8];
    {
        const float* kr = kT + ((size_t)b * NTOK + j0 + lane) * DQK;
#pragma unroll
        for (int u = 0; u < 8; ++u) kreg[u] = *(const f32x4*)(kr + 4 * u);
    }

    f32x4 acc[4][4]; // PV accumulator: row j = 16mt+qd*4+r, col c = 64wv+16ct+l15
#pragma unroll
    for (int mt = 0; mt < 4; ++mt)
#pragma unroll
        for (int ct = 0; ct < 4; ++ct)
            acc[mt][ct] = (f32x4){0.f, 0.f, 0.f, 0.f};
    float lw = 0.f; // exact per-j partial sum (j = j0+lane, this wave's i rows)

    const unsigned short* vrow =
        vcn + (size_t)b * CCH * NTOK + (size_t)(64 * wv + l15) * NTOK + qd * 8;
    const float* qsrc = qT + (size_t)b * NTOK * DQK;

    for (int i0 = 0; i0 < NTOK; i0 += BI) {
        // stage q chunk: 64 rows x 32 floats
        {
            const float* src = qsrc + (size_t)i0 * DQK;
#pragma unroll
            for (int h = 0; h < 2; ++h) {
                int f = t + 256 * h;             // float4 index in [0,512)
                int row = f >> 3, q4 = (f & 7) * 4;
                *(f32x4*)&qsh[row * QS + q4] = *(const f32x4*)(src + row * 32 + q4);
            }
        }
        __syncthreads(); // B1: qsh ready; prev iter's Pl reads (PV) done

        // prefetch V B-fragments: B[k=i_loc=32kc+qd*8+e][n=c=64wv+16ct+l15]
        short8 vf[2][4];
#pragma unroll
        for (int kc = 0; kc < 2; ++kc)
#pragma unroll
            for (int ct = 0; ct < 4; ++ct)
                vf[kc][ct] = *(const short8*)(vrow + (size_t)(16 * ct) * NTOK + i0 + 32 * kc);

        // QK (fp32): wave wv computes i_loc in [16wv,16wv+16), all j = lane
#pragma unroll
        for (int r = 0; r < 16; r += 2) {
            float s0 = 0.f, s1 = 0.f;
            int il = 16 * wv + r;
#pragma unroll
            for (int u = 0; u < 8; ++u) {
                f32x4 qa = *(const f32x4*)&qsh[il * QS + 4 * u];        // broadcast
                f32x4 qb = *(const f32x4*)&qsh[(il + 1) * QS + 4 * u];  // broadcast
                s0 += qa[0]*kreg[u][0] + qa[1]*kreg[u][1] + qa[2]*kreg[u][2] + qa[3]*kreg[u][3];
                s1 += qb[0]*kreg[u][0] + qb[1]*kreg[u][1] + qb[2]*kreg[u][2] + qb[3]*kreg[u][3];
            }
            float p0 = __expf(s0), p1 = __expf(s1);
            lw += p0 + p1;
            // Pl[j=lane][i_loc], i pairs packed (even r -> dword aligned)
            *(unsigned int*)(Pl + lane * SI + il) =
                (unsigned)f2bf(p0) | ((unsigned)f2bf(p1) << 16);
        }
        __syncthreads(); // B2: P visible to all waves

        // PV MFMA: A = P^T[j][i] from LDS (m=l15 -> j=16mt+l15, k=32kc+qd*8+e)
#pragma unroll
        for (int kc = 0; kc < 2; ++kc) {
            short8 pa[4];
#pragma unroll
            for (int mt = 0; mt < 4; ++mt)
                pa[mt] = *(const short8*)(Pl + (16 * mt + l15) * SI + 32 * kc + qd * 8);
#pragma unroll
            for (int mt = 0; mt < 4; ++mt)
#pragma unroll
                for (int ct = 0; ct < 4; ++ct)
                    acc[mt][ct] = __builtin_amdgcn_mfma_f32_16x16x32_bf16(
                        pa[mt], vf[kc][ct], acc[mt][ct], 0, 0, 0);
        }
    }

    // l[j]: 4 per-wave partials per j, exact fp32
    lred[wv * 64 + lane] = lw;
    __syncthreads(); // also: all PV reads done before epilogue aliases Pl

    const float g = gamma[0];
    float rl[4][4]; // gamma / l for acc row j = 16mt + qd*4 + r
#pragma unroll
    for (int mt = 0; mt < 4; ++mt)
#pragma unroll
        for (int r = 0; r < 4; ++r) {
            int j = 16 * mt + qd * 4 + r;
            float l = (lred[j] + lred[64 + j]) + (lred[128 + j] + lred[192 + j]);
            rl[mt][r] = g / l;
        }

    // epilogue: per-wave transpose through LDS, coalesced float4 store
    float* otl = (float*)smem + wv * (16 * SO); // 4352 B/wave, aliases qsh/Pl (dead)
#pragma unroll
    for (int ct = 0; ct < 4; ++ct) {
#pragma unroll
        for (int mt = 0; mt < 4; ++mt)
#pragma unroll
            for (int r = 0; r < 4; ++r)
                otl[l15 * SO + 16 * mt + qd * 4 + r] = acc[mt][ct][r] * rl[mt][r];
        // wave-internal transpose: DS ops in-order within a wave
#pragma unroll
        for (int rr = 0; rr < 4; ++rr) {
            int rloc = qd + 4 * rr;
            f32x4 o4 = *(f32x4*)(otl + rloc * SO + l15 * 4);
            int cg = 64 * wv + 16 * ct + rloc;
            size_t gaddr = ((size_t)(b * CCH + cg)) * NTOK + j0 + l15 * 4;
            f32x4 xv = *(const f32x4*)(x + gaddr);
            o4[0] += xv[0]; o4[1] += xv[1]; o4[2] += xv[2]; o4[3] += xv[3];
            *(f32x4*)(out + gaddr) = o4;
        }
    }
}

extern "C" void kernel_launch(void* const* d_in, const int* in_sizes, int n_in,
                              void* d_out, int out_size, void* d_ws, size_t ws_size,
                              hipStream_t stream) {
    const float* x     = (const float*)d_in[0];
    const float* w     = (const float*)d_in[1];
    const float* gamma = (const float*)d_in[2];
    float* out = (float*)d_out;

    float* qT = (float*)d_ws;                           // 2*9216*32 f32
    float* kT = qT + (size_t)2 * NTOK * DQK;            // 2*9216*32 f32
    unsigned short* vcn = (unsigned short*)(kT + (size_t)2 * NTOK * DQK); // 2*256*9216 bf16

    dim3 g1(NTOK / 256, 320 / 32, 2);
    qkv_kernel<<<g1, 256, 0, stream>>>(x, w, qT, kT, vcn);

    dim3 g2(NTOK / BJ, 2);
    attn_kernel<<<g2, 256, 0, stream>>>(qT, kT, vcn, x, gamma, out);
}

// Round 5
// 628.313 us; speedup vs baseline: 8.1670x; 1.3067x over previous
//
#include <hip/hip_runtime.h>
#include <hip/hip_bf16.h>

#define NTOK 9216   // H*W
#define CCH  256    // C
#define DQK  32     // CQ
#define BJ   32     // j-columns per attention block
#define BI   64     // i-rows per iteration
#define SI   72     // Pl row stride (shorts): 144B rows, 16B aligned
#define SO   36     // epilogue LDS row stride (floats)

typedef __attribute__((ext_vector_type(8))) short short8;
typedef __attribute__((ext_vector_type(4))) float f32x4;

__device__ __forceinline__ unsigned short f2bf(float x) {
    union { float f; unsigned int u; } v; v.f = x;
    return (unsigned short)((v.u + 0x7FFF + ((v.u >> 16) & 1)) >> 16); // RNE
}

// ---------------- Kernel 1: QKV projection ----------------
// qkv[o][n] = sum_c w[o][c] * x[b][c][n]
//   o in [0,32)   -> qT[b][n][o]      (bf16, n x 32)  QK A-side (i rows)
//   o in [32,64)  -> kT[b][n][o-32]   (bf16, n x 32)  QK B-side (j cols)
//   o in [64,320) -> vcn[b][o-64][n]  (bf16, c x n)   PV B-side
__global__ __launch_bounds__(256) void qkv_kernel(
    const float* __restrict__ x, const float* __restrict__ w,
    unsigned short* __restrict__ qT, unsigned short* __restrict__ kT,
    unsigned short* __restrict__ vcn)
{
    const int t  = threadIdx.x;
    const int n  = blockIdx.x * 256 + t;
    const int o0 = blockIdx.y * 32;
    const int b  = blockIdx.z;
    const float* xb = x + (size_t)b * CCH * NTOK + n;
    const float* wr = w + (size_t)o0 * CCH;   // uniform address -> s_load

    float acc[32];
#pragma unroll
    for (int o = 0; o < 32; ++o) acc[o] = 0.f;

#pragma unroll 8
    for (int c = 0; c < CCH; ++c) {
        float xv = xb[(size_t)c * NTOK];
#pragma unroll
        for (int o = 0; o < 32; ++o)
            acc[o] += wr[o * CCH + c] * xv;
    }

    if (o0 < 64) {
        unsigned short* dst = ((o0 == 0) ? qT : kT) + ((size_t)b * NTOK + n) * DQK;
#pragma unroll
        for (int o = 0; o < 32; ++o) dst[o] = f2bf(acc[o]); // contiguous; compiler vectorizes
    } else {
        unsigned short* dst = vcn + ((size_t)b * CCH + (o0 - 64)) * NTOK + n;
#pragma unroll
        for (int o = 0; o < 32; ++o)
            dst[(size_t)o * NTOK] = f2bf(acc[o]);           // lanes coalesce along n
    }
}

// ---------------- Kernel 2: full-MFMA flash attention ----------------
// S[i][j] = q[i]·k[j] via mfma (A=q rows, B=k rows), P=exp(S) -> Pl[j][i] bf16,
// exact l[j] from fp32 P in registers; O[j][c] += P^T @ V via mfma.
// out[b][c][j] = gamma*O[j][c]/l[j] + x[b][c][j]
__global__ __launch_bounds__(256) void attn_kernel(
    const unsigned short* __restrict__ qT, const unsigned short* __restrict__ kT,
    const unsigned short* __restrict__ vcn, const float* __restrict__ x,
    const float* __restrict__ gamma, float* __restrict__ out)
{
    // Pl [0,4608) bf16 32 x SI | epilogue otl aliases [0,9216) | lred [9216,9728)
    __shared__ __align__(16) char smem[9728];
    unsigned short* Pl = (unsigned short*)smem;
    float* lred = (float*)(smem + 9216);

    const int t    = threadIdx.x;
    const int wv   = t >> 6;
    const int lane = t & 63;
    const int l15  = lane & 15;
    const int qd   = lane >> 4;
    const int j0   = blockIdx.x * BJ;
    const int b    = blockIdx.y;

    const unsigned short* qTb = qT + (size_t)b * NTOK * DQK;

    // resident k B-frags: B[k=d=qd*8+e][n=j=16jt+l15]
    short8 kf[2];
#pragma unroll
    for (int jt = 0; jt < 2; ++jt)
        kf[jt] = *(const short8*)(kT + ((size_t)b * NTOK + j0 + 16 * jt + l15) * DQK + qd * 8);

    f32x4 acc[2][4]; // O[j = 16mt+4qd+r][c = 64wv+16ct+l15]
#pragma unroll
    for (int mt = 0; mt < 2; ++mt)
#pragma unroll
        for (int ct = 0; ct < 4; ++ct)
            acc[mt][ct] = (f32x4){0.f, 0.f, 0.f, 0.f};
    float lw[2] = {0.f, 0.f}; // per-lane partial l for j = 16jt+l15 (this wave's i rows)

    const unsigned short* qrow = qTb + (size_t)(16 * wv + l15) * DQK + qd * 8;
    const unsigned short* vrow =
        vcn + (size_t)b * CCH * NTOK + (size_t)(64 * wv + l15) * NTOK + qd * 8;

    for (int i0 = 0; i0 < NTOK; i0 += BI) {
        // A-frag of q rows: A[m=l15 -> i=i0+16wv+l15][k=d=qd*8+e]
        short8 af = *(const short8*)(qrow + (size_t)i0 * DQK);
        // V B-frags: B[k=i_loc=32kc+qd*8+e][n=c=64wv+16ct+l15]
        short8 vf[2][4];
#pragma unroll
        for (int kc = 0; kc < 2; ++kc)
#pragma unroll
            for (int ct = 0; ct < 4; ++ct)
                vf[kc][ct] = *(const short8*)(vrow + (size_t)(16 * ct) * NTOK + i0 + 32 * kc);

        // QK: s[jt][r] = S[i = i0+16wv+4qd+r][j = j0+16jt+l15]
        f32x4 s[2];
#pragma unroll
        for (int jt = 0; jt < 2; ++jt)
            s[jt] = __builtin_amdgcn_mfma_f32_16x16x32_bf16(
                af, kf[jt], (f32x4){0.f, 0.f, 0.f, 0.f}, 0, 0, 0);

        // P = exp(S); exact fp32 partial l; write P^T to Pl[j][i_loc]
#pragma unroll
        for (int jt = 0; jt < 2; ++jt) {
            float p0 = __expf(s[jt][0]);
            float p1 = __expf(s[jt][1]);
            float p2 = __expf(s[jt][2]);
            float p3 = __expf(s[jt][3]);
            lw[jt] += (p0 + p1) + (p2 + p3);
            int base = (16 * jt + l15) * SI + 16 * wv + 4 * qd; // i pairs dword-aligned
            *(unsigned int*)(Pl + base)     = (unsigned)f2bf(p0) | ((unsigned)f2bf(p1) << 16);
            *(unsigned int*)(Pl + base + 2) = (unsigned)f2bf(p2) | ((unsigned)f2bf(p3) << 16);
        }
        __syncthreads(); // B1: P visible to all waves

        // PV: A = Pl rows (m=l15 -> j=16mt+l15, k=i_loc=32kc+qd*8+e), B = vf
#pragma unroll
        for (int kc = 0; kc < 2; ++kc) {
            short8 pa[2];
#pragma unroll
            for (int mt = 0; mt < 2; ++mt)
                pa[mt] = *(const short8*)(Pl + (16 * mt + l15) * SI + 32 * kc + qd * 8);
#pragma unroll
            for (int mt = 0; mt < 2; ++mt)
#pragma unroll
                for (int ct = 0; ct < 4; ++ct)
                    acc[mt][ct] = __builtin_amdgcn_mfma_f32_16x16x32_bf16(
                        pa[mt], vf[kc][ct], acc[mt][ct], 0, 0, 0);
        }
        __syncthreads(); // B2: PV reads done before next iteration's P writes
    }

    // l[j]: reduce over qd (xor16/32), publish per-wave, sum 4 waves
#pragma unroll
    for (int jt = 0; jt < 2; ++jt) {
        lw[jt] += __shfl_xor(lw[jt], 16);
        lw[jt] += __shfl_xor(lw[jt], 32);
    }
    if (qd == 0) {
#pragma unroll
        for (int jt = 0; jt < 2; ++jt)
            lred[wv * 32 + 16 * jt + l15] = lw[jt];
    }
    __syncthreads(); // also: last PV reads done before otl aliases Pl

    const float g = gamma[0];
    float rl[2][4]; // gamma/l for acc row j = 16mt + 4qd + r
#pragma unroll
    for (int mt = 0; mt < 2; ++mt)
#pragma unroll
        for (int r = 0; r < 4; ++r) {
            int j = 16 * mt + 4 * qd + r;
            float l = (lred[j] + lred[32 + j]) + (lred[64 + j] + lred[96 + j]);
            rl[mt][r] = g / l;
        }

    // epilogue: per-wave 16c x 32j transpose through LDS, coalesced f32x4 stores
    float* otl = (float*)smem + wv * (16 * SO); // 2304 B/wave, aliases Pl (dead)
#pragma unroll
    for (int ct = 0; ct < 4; ++ct) {
#pragma unroll
        for (int mt = 0; mt < 2; ++mt)
#pragma unroll
            for (int r = 0; r < 4; ++r)
                otl[l15 * SO + 16 * mt + 4 * qd + r] = acc[mt][ct][r] * rl[mt][r];
        // wave-internal transpose: DS ops in-order within a wave (validated R4)
#pragma unroll
        for (int rr = 0; rr < 2; ++rr) {
            int f  = lane + 64 * rr;    // [0,128): 16 c-rows x 8 f32x4
            int cl = f >> 3;
            int j4 = (f & 7) * 4;
            f32x4 o4 = *(f32x4*)(otl + cl * SO + j4);
            int cg = 64 * wv + 16 * ct + cl;
            size_t gaddr = ((size_t)(b * CCH + cg)) * NTOK + j0 + j4;
            f32x4 xv = *(const f32x4*)(x + gaddr);
            o4[0] += xv[0]; o4[1] += xv[1]; o4[2] += xv[2]; o4[3] += xv[3];
            *(f32x4*)(out + gaddr) = o4;
        }
    }
}

extern "C" void kernel_launch(void* const* d_in, const int* in_sizes, int n_in,
                              void* d_out, int out_size, void* d_ws, size_t ws_size,
                              hipStream_t stream) {
    const float* x     = (const float*)d_in[0];
    const float* w     = (const float*)d_in[1];
    const float* gamma = (const float*)d_in[2];
    float* out = (float*)d_out;

    unsigned short* qT  = (unsigned short*)d_ws;          // 2*9216*32 bf16
    unsigned short* kT  = qT + (size_t)2 * NTOK * DQK;    // 2*9216*32 bf16
    unsigned short* vcn = kT + (size_t)2 * NTOK * DQK;    // 2*256*9216 bf16

    dim3 g1(NTOK / 256, 320 / 32, 2);
    qkv_kernel<<<g1, 256, 0, stream>>>(x, w, qT, kT, vcn);

    dim3 g2(NTOK / BJ, 2);
    attn_kernel<<<g2, 256, 0, stream>>>(qT, kT, vcn, x, gamma, out);
}